// Round 7
// baseline (1621.564 us; speedup 1.0000x reference)
//
#include <hip/hip_runtime.h>
#include <math.h>
#include <stdint.h>

#define NPTS 4096
#define KMAX 300
#define SORT_N 512
#define NTHR 256
#define NFEAT 336          // features computed for ranks 0..NFEAT-1 (covers tie runs past 300)
#define TIE_TOL 4u         // d2-bit ulp window treated as "reference order unknowable"

__global__ __launch_bounds__(NTHR) void ppf_kernel(
    const float* __restrict__ pts,
    const float* __restrict__ nrm,
    float* __restrict__ out)
{
    const int row = blockIdx.x;          // b*4096 + i
    const int b = row >> 12;
    const int i = row & (NPTS - 1);
    const int t = threadIdx.x;

    __shared__ uint32_t s_bits[NPTS];                 // 16 KB: fp32 d2 bit patterns
    __shared__ unsigned long long s_key[SORT_N];      // 4 KB: (d2bits<<32)|idx
    __shared__ float s_feat[NFEAT][4];                // 5.25 KB
    __shared__ uint32_t s_hist[256];
    __shared__ uint32_t s_sel[2];
    __shared__ uint32_t s_cnt;

    const float* ptsB = pts + (size_t)b * NPTS * 3;
    const float* nrmB = nrm + (size_t)b * NPTS * 3;

    const float pix = ptsB[3*i], piy = ptsB[3*i+1], piz = ptsB[3*i+2];
    const float nix = nrmB[3*i], niy = nrmB[3*i+1], niz = nrmB[3*i+2];

    // ---- 1. all-pairs squared distances (fp32, sequential, no fma) ----
    {
#pragma clang fp contract(off)
        const float sqi = pix*pix + piy*piy + piz*piz;
        for (int j = t; j < NPTS; j += NTHR) {
            float xj = ptsB[3*j], yj = ptsB[3*j+1], zj = ptsB[3*j+2];
            float sqj = xj*xj + yj*yj + zj*zj;
            float dot = pix*xj + piy*yj + piz*zj;
            float d2 = sqi + sqj - 2.0f*dot;
            d2 = fmaxf(d2, 0.0f);
            s_bits[j] = __float_as_uint(d2);   // nonneg float: bits order-monotone
        }
    }
    __syncthreads();

    // ---- 2. radix-select the KMAX-th smallest d2 value ----
    uint32_t prefix = 0;
    int k = KMAX;
    for (int pass = 0; pass < 4; ++pass) {
        const int shift = 24 - 8*pass;
        s_hist[t] = 0;
        __syncthreads();
        const uint32_t mask = (pass == 0) ? 0u : (0xFFFFFFFFu << (shift + 8));
        for (int j = t; j < NPTS; j += NTHR) {
            uint32_t v = s_bits[j];
            if ((v & mask) == prefix)
                atomicAdd(&s_hist[(v >> shift) & 255u], 1u);
        }
        __syncthreads();
        if (t == 0) {
            int acc = 0;
            uint32_t bin = 0;
            for (;; ++bin) {
                int c = (int)s_hist[bin];
                if (acc + c >= k) break;
                acc += c;
            }
            s_sel[0] = bin;
            s_sel[1] = (uint32_t)acc;
        }
        __syncthreads();
        prefix |= (s_sel[0] << shift);
        k -= (int)s_sel[1];
        __syncthreads();
    }
    const uint32_t V = prefix;   // d2 bits of the 300th smallest

    // ---- 3. collect all <= V + TIE_TOL; sort by (d2bits asc, index asc) ----
    if (t == 0) s_cnt = 0;
    __syncthreads();
    for (int j = t; j < NPTS; j += NTHR) {
        uint32_t v = s_bits[j];
        if (v <= V + TIE_TOL) {
            uint32_t pos = atomicAdd(&s_cnt, 1u);
            if (pos < SORT_N)
                s_key[pos] = ((unsigned long long)v << 32) | (uint32_t)j;
        }
    }
    __syncthreads();
    const int total = (int)(s_cnt < (uint32_t)SORT_N ? s_cnt : (uint32_t)SORT_N);
    for (int p = t; p < SORT_N; p += NTHR)
        if (p >= total) s_key[p] = ~0ULL;

    for (int ksz = 2; ksz <= SORT_N; ksz <<= 1) {
        for (int jsz = ksz >> 1; jsz > 0; jsz >>= 1) {
            __syncthreads();
            for (int e = t; e < SORT_N; e += NTHR) {
                int partner = e ^ jsz;
                if (partner > e) {
                    unsigned long long a = s_key[e];
                    unsigned long long c = s_key[partner];
                    bool up = ((e & ksz) == 0);
                    if ((a > c) == up) { s_key[e] = c; s_key[partner] = a; }
                }
            }
        }
    }
    __syncthreads();

    const int nfeat = (total < NFEAT) ? total : NFEAT;

    // ---- 4. PPF features for ranks 0..nfeat-1 ----
    const float inv_pi = 0.31830988618379067154f;
    for (int r = t; r < nfeat; r += NTHR) {
        int j = (int)(uint32_t)(s_key[r] & 0xFFFFu);
        float xj = ptsB[3*j], yj = ptsB[3*j+1], zj = ptsB[3*j+2];
        float mx = nrmB[3*j], my = nrmB[3*j+1], mz = nrmB[3*j+2];
        float dx = xj - pix, dy = yj - piy, dz = zj - piz;
        float d = sqrtf(dx*dx + dy*dy + dz*dz);

        float y1 = nix*dx + niy*dy + niz*dz;
        float c1x = niy*dz - niz*dy, c1y = niz*dx - nix*dz, c1z = nix*dy - niy*dx;
        float x1 = sqrtf(c1x*c1x + c1y*c1y + c1z*c1z);
        float a1 = atan2f(x1, y1) * inv_pi;

        float y2 = mx*dx + my*dy + mz*dz;
        float c2x = my*dz - mz*dy, c2y = mz*dx - mx*dz, c2z = mx*dy - my*dx;
        float x2 = sqrtf(c2x*c2x + c2y*c2y + c2z*c2z);
        float a2 = atan2f(x2, y2) * inv_pi;

        float y3 = nix*mx + niy*my + niz*mz;
        float c3x = niy*mz - niz*my, c3y = niz*mx - nix*mz, c3z = nix*my - niy*mx;
        float x3 = sqrtf(c3x*c3x + c3y*c3y + c3z*c3z);
        float a3 = atan2f(x3, y3) * inv_pi;

        // Self-point: reference reductions (np.sum / lax.reduce) init the
        // accumulator with +0.0, so y = +0 even when all products are -0;
        // arctan2(+0,+0) = 0 -> a1 = a2 = 0 unconditionally. d = 0.
        if (j == i) { d = 0.0f; a1 = 0.0f; a2 = 0.0f; }

        s_feat[r][0] = d; s_feat[r][1] = a1; s_feat[r][2] = a2; s_feat[r][3] = a3;
    }
    __syncthreads();

    // ---- 5. band means with tie-run smoothing at boundaries ----
    if (t < 24) {
        const int band = t >> 2, f = t & 3;
        const int lo = (band == 0) ? 0 : (10 << (band - 1));
        const int hi = (band == 5) ? 300 : (10 << band);
        const int T = nfeat;

        float sum = 0.f;
        int mid_lo = lo;
        int mid_hi = (hi < T) ? hi : T;

        #define BITS(r) ((uint32_t)(s_key[(r)] >> 32))
        #define CHAINED(r) (BITS(r) - BITS((r)-1) <= TIE_TOL)

        if (lo > 0 && lo < T && CHAINED(lo)) {
            int a = lo - 1; while (a > 0 && CHAINED(a)) --a;
            int bq = lo;    while (bq + 1 < T && CHAINED(bq + 1)) ++bq;
            float w = (float)(bq + 1 - lo) / (float)(bq + 1 - a);
            for (int r = a; r <= bq; ++r) sum += w * s_feat[r][f];
            mid_lo = bq + 1;
        }
        if (hi < T && CHAINED(hi)) {
            int a = hi - 1; while (a > 0 && CHAINED(a)) --a;
            int bq = hi;    while (bq + 1 < T && CHAINED(bq + 1)) ++bq;
            float w = (float)(hi - a) / (float)(bq + 1 - a);
            for (int r = a; r <= bq; ++r) sum += w * s_feat[r][f];
            mid_hi = a;
        }
        #undef BITS
        #undef CHAINED

        for (int r = mid_lo; r < mid_hi; ++r) sum += s_feat[r][f];
        out[(size_t)row * 24 + band * 4 + f] = sum / (float)(hi - lo);
    }
}

extern "C" void kernel_launch(void* const* d_in, const int* in_sizes, int n_in,
                              void* d_out, int out_size, void* d_ws, size_t ws_size,
                              hipStream_t stream) {
    (void)n_in; (void)out_size; (void)d_ws; (void)ws_size;
    const float* pts = (const float*)d_in[0];
    const float* nrm = (const float*)d_in[1];
    float* out = (float*)d_out;
    const int rows = in_sizes[0] / 3;   // b * n = 32768
    ppf_kernel<<<dim3(rows), dim3(NTHR), 0, stream>>>(pts, nrm, out);
}

// Round 10
// 643.388 us; speedup vs baseline: 2.5204x; 2.5204x over previous
//
#include <hip/hip_runtime.h>
#include <math.h>
#include <stdint.h>

#define NPTS 4096
#define KMAX 300
#define SORT_N 512
#define NTHR 256
#define PERTHR 16            // NPTS / NTHR
#define NFEAT 336            // features kept for ranks < NFEAT
#define TIE_TOL 4u           // full-bits ulp window: "reference order unknowable"
#define NBIN 4096            // stage-1 histogram on bits>>20

typedef unsigned long long u64;

// EXACT d2 rounding (matches R7): sequential, no fma, fmax 0.
__device__ __forceinline__ uint32_t d2_bits(float pix, float piy, float piz, float sqi,
                                            const float* __restrict__ ptsB, int j) {
#pragma clang fp contract(off)
    float xj = ptsB[3*j], yj = ptsB[3*j+1], zj = ptsB[3*j+2];
    float sqj = xj*xj + yj*yj + zj*zj;
    float dot = pix*xj + piy*yj + piz*zj;
    float d2 = sqi + sqj - 2.0f*dot;
    d2 = fmaxf(d2, 0.0f);
    return __float_as_uint(d2);          // nonneg float: bits are order-monotone
}

__global__ __launch_bounds__(NTHR) void ppf_kernel(
    const float* __restrict__ pts,
    const float* __restrict__ nrm,
    float* __restrict__ out)
{
    const int row = blockIdx.x;          // b*4096 + i
    const int b = row >> 12;
    const int i = row & (NPTS - 1);
    const int t = threadIdx.x;

    // phase A: s_buf = uint32 hist[4096] (16 KB)
    // phase B/C: s_buf = u64 key[512] (4 KB) + float feat[336][4] (5.25 KB)
    __shared__ __align__(16) unsigned char s_buf[NBIN * 4];
    uint32_t* s_hist = (uint32_t*)s_buf;
    u64* s_key = (u64*)s_buf;
    float (*s_feat)[4] = (float(*)[4])(s_buf + SORT_N * 8);
    __shared__ uint32_t s_gsum[NTHR];    // stage-1 group sums, then stage-2 hist2
    __shared__ uint32_t s_sel;           // stage1: sel1; stage2: 20-bit prefix P
    __shared__ uint32_t s_below;         // count of elements with code < sel1
    __shared__ uint32_t s_cnt;

    const float* ptsB = pts + (size_t)b * NPTS * 3;
    const float* nrmB = nrm + (size_t)b * NPTS * 3;

    const float pix = ptsB[3*i], piy = ptsB[3*i+1], piz = ptsB[3*i+2];
    const float nix = nrmB[3*i], niy = nrmB[3*i+1], niz = nrmB[3*i+2];
    float sqi;
    {
#pragma clang fp contract(off)
        sqi = pix*pix + piy*piy + piz*piz;
    }

    // ---- A0: zero histogram ----
    for (int q = t; q < NBIN; q += NTHR) s_hist[q] = 0;
    if (t == 0) s_cnt = 0;
    __syncthreads();                                          // #1

    // ---- A1: full d2 bits in registers + 12-bit histogram ----
    uint32_t bits[PERTHR];
#pragma unroll
    for (int q = 0; q < PERTHR; ++q) {
        int j = q * NTHR + t;
        bits[q] = d2_bits(pix, piy, piz, sqi, ptsB, j);
        atomicAdd(&s_hist[bits[q] >> 20], 1u);
    }
    __syncthreads();                                          // #2

    // ---- A2: per-thread 16-bin group sums ----
    {
        const uint4* H4 = (const uint4*)s_hist;
        uint32_t gs = 0;
#pragma unroll
        for (int q = 0; q < 4; ++q) {
            uint4 v = H4[t*4 + q];
            gs += v.x + v.y + v.z + v.w;
        }
        s_gsum[t] = gs;
    }
    __syncthreads();                                          // #3

    // ---- A3: t0 scan -> sel1 (bin of rank KMAX) + below1 ----
    if (t == 0) {
        uint32_t acc = 0, below = 0, selbin = 0;
        int found = 0;
        for (int g = 0; g < NTHR && !found; ++g) {
            uint32_t gs = s_gsum[g];
            if (acc + gs >= KMAX) {
                uint32_t a = acc;
                for (int q = 0; q < 16; ++q) {
                    uint32_t c = s_hist[g*16 + q];
                    if (a + c >= KMAX) { selbin = (uint32_t)(g*16 + q); below = a; break; }
                    a += c;
                }
                found = 1;
            } else acc += gs;
        }
        s_sel = selbin;
        s_below = below;
    }
    __syncthreads();                                          // #4
    const uint32_t sel1 = s_sel;

    // ---- A4: stage-2 hist (256 bins on bits[19:12], restricted to bin sel1) ----
    s_gsum[t] = 0;
    __syncthreads();                                          // #5
#pragma unroll
    for (int q = 0; q < PERTHR; ++q) {
        if ((bits[q] >> 20) == sel1)
            atomicAdd(&s_gsum[(bits[q] >> 12) & 255u], 1u);
    }
    __syncthreads();                                          // #6

    // ---- A5: t0 scan -> exact 20-bit prefix P of rank-KMAX element ----
    if (t == 0) {
        uint32_t k2 = KMAX - s_below;       // >= 1
        uint32_t a = 0, s2 = 0;
        for (int q2 = 0; q2 < 256; ++q2) {
            uint32_t c = s_gsum[q2];
            if (a + c >= k2) { s2 = (uint32_t)q2; break; }
            a += c;
        }
        s_sel = (sel1 << 8) | s2;
    }
    __syncthreads();                                          // #7
    const uint32_t P = s_sel;

    // ---- B1: collect (bits>>12) <= P+1  (superset of top-300 + 4-ulp tie window; M ~ 302) ----
#pragma unroll
    for (int q = 0; q < PERTHR; ++q) {
        if ((bits[q] >> 12) <= P + 1) {
            int j = q * NTHR + t;
            uint32_t pos = atomicAdd(&s_cnt, 1u);
            if (pos < SORT_N)
                s_key[pos] = ((u64)bits[q] << 32) | (uint32_t)j;
        }
    }
    __syncthreads();                                          // #8
    const int M = (int)((s_cnt < (uint32_t)SORT_N) ? s_cnt : (uint32_t)SORT_N);
    const int T = (M < NFEAT) ? M : NFEAT;

    // ---- B2: rank by counting (broadcast LDS reads; keys unique via index bits) ----
    u64 k0 = (t < M) ? s_key[t] : ~0ull;
    u64 k1 = (t + NTHR < M) ? s_key[t + NTHR] : ~0ull;
    int r0 = 0, r1 = 0;
#pragma unroll 4
    for (int r = 0; r < M; ++r) {
        u64 kr = s_key[r];
        r0 += (kr < k0);
        r1 += (kr < k1);
    }
    __syncthreads();                                          // #9 (all reads done)
    if (t < M)        s_key[r0] = k0;                         // scatter -> sorted
    if (t + NTHR < M) s_key[r1] = k1;

    // ---- C1: PPF features for own elements (rank < T) ----
    const float inv_pi = 0.31830988618379067154f;
#pragma unroll
    for (int e = 0; e < 2; ++e) {
        int rk = e ? r1 : r0;
        u64 kk = e ? k1 : k0;
        bool live = e ? (t + NTHR < M) : (t < M);
        if (live && rk < T) {
            int j = (int)(uint32_t)(kk & 0xFFFFFFFFull);
            float xj = ptsB[3*j], yj = ptsB[3*j+1], zj = ptsB[3*j+2];
            float mx = nrmB[3*j], my = nrmB[3*j+1], mz = nrmB[3*j+2];
            float dx = xj - pix, dy = yj - piy, dz = zj - piz;
            float d = sqrtf(dx*dx + dy*dy + dz*dz);

            float y1 = nix*dx + niy*dy + niz*dz;
            float c1x = niy*dz - niz*dy, c1y = niz*dx - nix*dz, c1z = nix*dy - niy*dx;
            float x1 = sqrtf(c1x*c1x + c1y*c1y + c1z*c1z);
            float a1 = atan2f(x1, y1) * inv_pi;

            float y2 = mx*dx + my*dy + mz*dz;
            float c2x = my*dz - mz*dy, c2y = mz*dx - mx*dz, c2z = mx*dy - my*dx;
            float x2 = sqrtf(c2x*c2x + c2y*c2y + c2z*c2z);
            float a2 = atan2f(x2, y2) * inv_pi;

            float y3 = nix*mx + niy*my + niz*mz;
            float c3x = niy*mz - niz*my, c3y = niz*mx - nix*mz, c3z = nix*my - niy*mx;
            float x3 = sqrtf(c3x*c3x + c3y*c3y + c3z*c3z);
            float a3 = atan2f(x3, y3) * inv_pi;

            // self-point: reference reductions init accumulator with +0.0 ->
            // y = +0 regardless of signed-zero products -> arctan2(+0,+0)=0.
            if (j == i) { d = 0.0f; a1 = 0.0f; a2 = 0.0f; }

            s_feat[rk][0] = d; s_feat[rk][1] = a1; s_feat[rk][2] = a2; s_feat[rk][3] = a3;
        }
    }
    __syncthreads();                                          // #10

    // ---- C2: band means with tie-run smoothing at boundaries (identical to R7) ----
    if (t < 24) {
        const int band = t >> 2, f = t & 3;
        const int lo = (band == 0) ? 0 : (10 << (band - 1));
        const int hi = (band == 5) ? 300 : (10 << band);

        float sum = 0.f;
        int mid_lo = lo;
        int mid_hi = (hi < T) ? hi : T;

        #define BITS(r) ((uint32_t)(s_key[(r)] >> 32))
        #define CHAINED(r) (BITS(r) - BITS((r)-1) <= TIE_TOL)

        if (lo > 0 && lo < T && CHAINED(lo)) {
            int a = lo - 1; while (a > 0 && CHAINED(a)) --a;
            int bq = lo;    while (bq + 1 < T && CHAINED(bq + 1)) ++bq;
            float w = (float)(bq + 1 - lo) / (float)(bq + 1 - a);
            for (int r = a; r <= bq; ++r) sum += w * s_feat[r][f];
            mid_lo = bq + 1;
        }
        if (hi < T && CHAINED(hi)) {
            int a = hi - 1; while (a > 0 && CHAINED(a)) --a;
            int bq = hi;    while (bq + 1 < T && CHAINED(bq + 1)) ++bq;
            float w = (float)(hi - a) / (float)(bq + 1 - a);
            for (int r = a; r <= bq; ++r) sum += w * s_feat[r][f];
            mid_hi = a;
        }
        #undef BITS
        #undef CHAINED

        for (int r = mid_lo; r < mid_hi; ++r) sum += s_feat[r][f];
        out[(size_t)row * 24 + band * 4 + f] = sum / (float)(hi - lo);
    }
}

extern "C" void kernel_launch(void* const* d_in, const int* in_sizes, int n_in,
                              void* d_out, int out_size, void* d_ws, size_t ws_size,
                              hipStream_t stream) {
    (void)n_in; (void)out_size; (void)d_ws; (void)ws_size;
    const float* pts = (const float*)d_in[0];
    const float* nrm = (const float*)d_in[1];
    float* out = (float*)d_out;
    const int rows = in_sizes[0] / 3;   // b * n = 32768
    ppf_kernel<<<dim3(rows), dim3(NTHR), 0, stream>>>(pts, nrm, out);
}